// Round 17
// baseline (119.518 us; speedup 1.0000x reference)
//
#include <hip/hip_runtime.h>
#include <math.h>

#define T_LEN   16384
#define NBATCH  8
#define NBLK    6
#define TILE    256
#define HALO    63
#define NTHR    768          // 12 waves; each wave owns 32 rows (2 m-tiles)
#define NWAVE   12
#define NROWS   384          // TILE + 2*HALO = 382, padded to 384
#define NTILES  64
#define HS      18           // f16 row stride in dwords (72 B)
#define HBUF    (NROWS * HS) // one h buffer in dwords

// workspace layout (dwords)
#define WS_CONV 0             // [i6][tap3][nt4][lane64][dw4] = 18432
#define WS_SKIP 18432         // [i6][nt2][lane64][dw4]      = 3072
#define WS_FIN  21504         // [nt2][lane64][dw4]          = 512
#define WS_LOG  22016         // 16 floats logits
#define WS_CNT  22032         // 1 uint completion counter
#define PREP_N  22016
#define PREP_TOT 22036

// per-iter LDS weight stage: 12 conv chunks + 2 skip chunks, 256 dw each
#define STG_CONV 0            // [tap3][nt4][lane64][dw4] = 3072 dw
#define STG_SKIP 3072         // [nt2][lane64][dw4]       = 512 dw
#define STG_TOT  3584         // 14336 B

// exp2-domain pre-scaling: tanh path x 2*log2(e), sigmoid path x log2(e).
#define SCALE_T 2.8853900817779268f
#define SCALE_S 1.4426950408889634f

typedef _Float16 half8 __attribute__((ext_vector_type(8)));
typedef __fp16  fp16x2 __attribute__((ext_vector_type(2)));   // cvt_pkrtz result type
typedef _Float16 h2v   __attribute__((ext_vector_type(2)));   // arithmetic type
typedef float f32x4  __attribute__((ext_vector_type(4)));

union HPK { unsigned u; _Float16 h[2]; fp16x2 pk; h2v v; };   // same 32 bits, two views
union AFR { uint2 u2[2]; half8 v; };

__device__ __forceinline__ unsigned packh(float a, float b) {   // 1x v_cvt_pkrtz_f16_f32
    HPK r; r.pk = __builtin_amdgcn_cvt_pkrtz(a, b); return r.u;
}
__device__ __forceinline__ h2v u2h(unsigned u) { HPK c; c.u = u; return c.v; }
__device__ __forceinline__ unsigned h2u(h2v h) { HPK c; c.v = h; return c.u; }
// packed relu: v_pk_max_f16 with 0
__device__ __forceinline__ h2v pkmax0(h2v a) {
    const h2v z = {(_Float16)0.0f, (_Float16)0.0f};
    return __builtin_elementwise_max(a, z);
}

// K-slot <-> logical-channel permutation shared by ALL operand-swapped MFMAs.
__device__ __forceinline__ int perm_ch(int g, int j) {
    return j < 4 ? 4 * g + j : 16 + 4 * g + (j - 4);
}

// tanh*sigmoid on PRE-SCALED args (exp2 domain). 3 quarter-rate ops.
__device__ __forceinline__ float gated(float a, float b) {
    float ea  = __builtin_amdgcn_exp2f(-fabsf(a));   // v_exp_f32 w/ -abs modifier
    float fb  = __builtin_amdgcn_exp2f(-b);          // v_exp_f32 w/ neg modifier
    float num = 1.0f - ea;
    float den = (1.0f + ea) * (1.0f + fb);
    float t   = num * __builtin_amdgcn_rcpf(den);
    return __builtin_copysignf(t, a);
}
__device__ __forceinline__ float relu(float x) { return fmaxf(x, 0.0f); }

// async global->LDS DMA, 16B per lane, wave-linear dest (base + lane*16)
__device__ __forceinline__ void gl_lds16(const unsigned* g, unsigned* l) {
    __builtin_amdgcn_global_load_lds(
        (const __attribute__((address_space(1))) void*)g,
        (__attribute__((address_space(3))) void*)l, 16, 0, 0);
}

#define MFMA(a, b, c) __builtin_amdgcn_mfma_f32_16x16x32_f16((a), (b), (c), 0, 0, 0)

// ---------------- weight prep: fp32 -> f16 A-fragments (operand-swapped) ----------------
__global__ void wavenet_prep(const float* __restrict__ wt, const float* __restrict__ wsg,
                             const float* __restrict__ wsk, const float* __restrict__ wfin,
                             unsigned* __restrict__ out)
{
    int id = blockIdx.x * 256 + threadIdx.x;
    if (id >= PREP_TOT) return;
    if (id >= PREP_N) { out[id] = 0u; return; }   // zero logits + counter
    int dw = id & 3, lane = (id >> 2) & 63;
    int g = lane >> 4, nlo = lane & 15;
    int ci0 = perm_ch(g, 2 * dw), ci1 = perm_ch(g, 2 * dw + 1);
    float v0, v1;
    if (id < WS_SKIP) {
        int nt = (id >> 8) & 3; int q = id >> 10;  // q = i*3+tap
        int tap = q % 3, i = q / 3;
        int co = (nt & 1) * 16 + nlo;
        const float* src = (nt < 2) ? wt : wsg;
        float sc = (nt < 2) ? SCALE_T : SCALE_S;
        v0 = src[((i * 3 + tap) * 32 + ci0) * 32 + co] * sc;
        v1 = src[((i * 3 + tap) * 32 + ci1) * 32 + co] * sc;
    } else if (id < WS_FIN) {
        int t = id - WS_SKIP;
        int nt = (t >> 8) & 1; int i = t >> 9;
        int co = nt * 16 + nlo;
        v0 = wsk[(i * 32 + ci0) * 32 + co];
        v1 = wsk[(i * 32 + ci1) * 32 + co];
    } else {
        int t = id - WS_FIN;
        int nt = (t >> 8) & 1;
        int co = nt * 16 + nlo;
        v0 = wfin[ci0 * 32 + co];
        v1 = wfin[ci1 * 32 + co];
    }
    HPK r; r.h[0] = (_Float16)v0; r.h[1] = (_Float16)v1;   // RNE for weights
    out[id] = r.u;
}

// ---------------- main fused kernel ----------------
// Ladder: r23 operand-swapped MFMAs (z in regs, conflicts 1.87M->98K);
// r24 liveness schedule; r27 packed-f16 epilogue; r28 exp2-domain gates;
// r29 segment-fused conv (shared weight reads, hold = tap-1 fragment) ->
// 41.3us main / 115.8us harness, WRITE 4.6MB (~3-dword spill, conv peak
// ~86 regs vs 85 cap). r30's pressure fixes REGRESSED (source order does not
// control scheduler liveness). r28/r29 parity falsified pure DS-bound model:
// kernel is lockstep-latency-bound (12 barrier phases + DMA drain).
// r31 (this round): EARLY STAGING BARRIER. Gates read no wstage data, so the
// staging barrier + DMA issue move before them: conv -> skw -> [bar, STAGE]
// -> gates -> BACK -> [bar]. DMA cover grows ~250 -> ~700 cy (gates' 48
// quarter-rate transcendentals + BACK), hiding the L2-hot fetch that was
// exposed at the iter-end vmcnt(0) drain. Conv-peak liveness untouched;
// post-barrier peak (~55 regs) stays below the conv peak -> no new spill.
// WRITE>5MB = pressure regression -> revert to r29.
// Ordering by barriers only (r21: NEVER volatile on LDS pointers).
__global__ __launch_bounds__(NTHR, 6)
void wavenet_main(const float* __restrict__ x,
                  const float* __restrict__ w_init, const float* __restrict__ b_init,
                  const float* __restrict__ b_tanh, const float* __restrict__ b_sig,
                  const float* __restrict__ b_skip, const float* __restrict__ b_final,
                  const float* __restrict__ b_dense,
                  const float* __restrict__ w_dense,
                  const unsigned* __restrict__ wsB,
                  float* __restrict__ logits, unsigned* __restrict__ counter,
                  float* __restrict__ out)
{
    __shared__ unsigned h_pack[2 * HBUF];      // double-buffered, 55296 B
    __shared__ unsigned wstage[STG_TOT];       // per-iter weight stage, 14336 B
    __shared__ unsigned x_s[NROWS];            // packed f16 (xv,xv), 1536 B
    __shared__ float bias_s[3 * NBLK * 32];    // [t/s/k][i][ch], 2304 B (t/s pre-scaled)
    __shared__ unsigned wibp_s[32];            // packed f16 w_init[16] + b_init[16], slot order
    __shared__ float red[NWAVE][2];

    const int tid  = threadIdx.x;
    const int lane = tid & 63;
    const int wv   = tid >> 6;               // 0..11; wave owns rows [wv*32, wv*32+32)
    const int tile = blockIdx.x & (NTILES - 1);
    const int b    = blockIdx.x >> 6;
    const int col0 = lane & 15;              // = time-row within 16-row segment
    const int g4   = lane >> 4;              // k-slot group / slot quad

    // stage iter-`it` weights: wave wv takes conv chunk wv, waves 0/1 also skip chunks
    #define STAGE_ITER(it) do {                                                   \
        const unsigned* _s = wsB + (it) * 3072 + wv * 256 + (lane << 2);          \
        gl_lds16(_s, wstage + wv * 256 + (lane << 2));                            \
        if (wv < 2) {                                                             \
            const unsigned* _s2 = wsB + WS_SKIP + (it) * 512 + wv * 256 + (lane << 2); \
            gl_lds16(_s2, wstage + STG_SKIP + wv * 256 + (lane << 2));            \
        }                                                                         \
    } while (0)

    // skip MFMA + packed-f16 h update for one segment. ZF/HB/skw/bk all in regs.
    #define BACK_SEG(ROW0, ZF, HBA, HBB) do {                                     \
        f32x4 s0 = bk_lo, s1 = bk_hi;                                             \
        s0 = MFMA(skw0, (ZF).v, s0);                                              \
        s1 = MFMA(skw1, (ZF).v, s1);                                              \
        const int row = (ROW0) + col0;                                            \
        h2v n0 = pkmax0(u2h(packh(s0[0], s0[1]))) + u2h((HBA).x);                 \
        h2v n1 = pkmax0(u2h(packh(s0[2], s0[3]))) + u2h((HBA).y);                 \
        h2v n2 = pkmax0(u2h(packh(s1[0], s1[1]))) + u2h((HBB).x);                 \
        h2v n3 = pkmax0(u2h(packh(s1[2], s1[3]))) + u2h((HBB).y);                 \
        unsigned pk0, pk1, pk2, pk3;                                              \
        if (!ilast) {                                                             \
            int tgr = tile * TILE - HALO + row;                                   \
            bool vr = (tgr >= 0) && (tgr < T_LEN);                                \
            pk0 = vr ? h2u(n0) : 0u;                                              \
            pk1 = vr ? h2u(n1) : 0u;                                              \
            pk2 = vr ? h2u(n2) : 0u;                                              \
            pk3 = vr ? h2u(n3) : 0u;                                              \
        } else {                                                                  \
            h2v xh = u2h(x_s[row]);                                               \
            uint2 wpA = *(const uint2*)&wibp_s[4 * g4];                           \
            uint2 wpB = *(const uint2*)&wibp_s[4 * g4 + 2];                       \
            uint2 bpA = *(const uint2*)&wibp_s[16 + 4 * g4];                      \
            uint2 bpB = *(const uint2*)&wibp_s[16 + 4 * g4 + 2];                  \
            h2v h00 = pkmax0(xh * u2h(wpA.x) + u2h(bpA.x));                       \
            h2v h01 = pkmax0(xh * u2h(wpA.y) + u2h(bpA.y));                       \
            h2v h02 = pkmax0(xh * u2h(wpB.x) + u2h(bpB.x));                       \
            h2v h03 = pkmax0(xh * u2h(wpB.y) + u2h(bpB.y));                       \
            pk0 = h2u(pkmax0(n0 - h00));                                          \
            pk1 = h2u(pkmax0(n1 - h01));                                          \
            pk2 = h2u(pkmax0(n2 - h02));                                          \
            pk3 = h2u(pkmax0(n3 - h03));                                          \
        }                                                                         \
        unsigned* hw = nxt + row * HS + g4 * 4;                                   \
        *(uint2*)hw = make_uint2(pk0, pk1);                                       \
        *(uint2*)(hw + 2) = make_uint2(pk2, pk3);                                 \
    } while (0)

    // ---- issue DMA for iter-0 weights immediately (lands before first barrier drain) ----
    STAGE_ITER(0);

    // ---- stage biases (gate paths pre-scaled) + packed init weights into LDS ----
    if (tid < 3 * NBLK * 32) {
        int which = tid / (NBLK * 32), r = tid % (NBLK * 32);
        float v = (which == 0) ? b_tanh[r] * SCALE_T
                : (which == 1) ? b_sig[r] * SCALE_S : b_skip[r];
        bias_s[tid] = v;
    } else if (tid < 3 * NBLK * 32 + 16) {
        int q  = tid - 3 * NBLK * 32;            // dword 0..15 (slot order)
        int c0 = perm_ch((2 * q) >> 3, (2 * q) & 7);
        int c1 = perm_ch((2 * q + 1) >> 3, (2 * q + 1) & 7);
        HPK w; w.h[0] = (_Float16)w_init[c0]; w.h[1] = (_Float16)w_init[c1];
        HPK bb2; bb2.h[0] = (_Float16)b_init[c0]; bb2.h[1] = (_Float16)b_init[c1];
        wibp_s[q]      = w.u;
        wibp_s[16 + q] = bb2.u;
    }

    // ---- init conv (CIN=1) -> f16 h in buf0 (SLOT channel order); 2 threads/row ----
    {
        int j    = tid >> 1;                 // row 0..383
        int half = tid & 1;                  // dwords half*8 .. half*8+7
        int tg = tile * TILE - HALO + j;
        bool valid = (tg >= 0) && (tg < T_LEN);
        float xv = valid ? x[(size_t)b * T_LEN + tg] : 0.0f;
        x_s[j] = packh(xv, xv);              // both halves write same value (benign)
        unsigned* hp = &h_pack[j * HS + half * 8];
        #pragma unroll
        for (int q = 0; q < 4; ++q) {
            unsigned pk[2];
            #pragma unroll
            for (int e = 0; e < 2; ++e) {
                int D  = half * 8 + 2 * q + e;           // dword index in row
                int s0 = 2 * D, s1 = 2 * D + 1;          // slot indices
                int c0 = perm_ch(s0 >> 3, s0 & 7);
                int c1 = perm_ch(s1 >> 3, s1 & 7);
                float f0 = relu(fmaf(xv, w_init[c0], b_init[c0]));
                float f1 = relu(fmaf(xv, w_init[c1], b_init[c1]));
                pk[e] = valid ? packh(f0, f1) : 0u;
            }
            *(uint2*)(hp + 2 * q) = make_uint2(pk[0], pk[1]);
        }
    }
    __syncthreads();    // drains vmcnt too -> iter-0 weight DMA landed

    #pragma unroll
    for (int i = 0; i < NBLK; ++i) {
        const int d = 1 << i;
        const unsigned* cur = &h_pack[(i & 1) * HBUF];
        unsigned*       nxt = &h_pack[((i + 1) & 1) * HBUF];
        const bool ilast = (i == NBLK - 1);
        const int row0a = wv * 32;
        const int row0b = wv * 32 + 16;

        // ---- fused conv: both segments share each tap's weight read ----
        // bias C-inits read ONCE, copied into both segments' accumulators.
        f32x4 bt_lo = *(const f32x4*)&bias_s[0 * NBLK * 32 + i * 32 + 4 * g4];
        f32x4 bt_hi = *(const f32x4*)&bias_s[0 * NBLK * 32 + i * 32 + 16 + 4 * g4];
        f32x4 bs_lo = *(const f32x4*)&bias_s[1 * NBLK * 32 + i * 32 + 4 * g4];
        f32x4 bs_hi = *(const f32x4*)&bias_s[1 * NBLK * 32 + i * 32 + 16 + 4 * g4];
        f32x4 a0 = bt_lo, a1 = bt_hi, a2 = bs_lo, a3 = bs_hi;   // seg0
        f32x4 a4 = bt_lo, a5 = bt_hi, a6 = bs_lo, a7 = bs_hi;   // seg1
        uint2 hb0a, hb0b, hb1a, hb1b;                           // tap-1 frags = hold

        #pragma unroll
        for (int tap = 0; tap < 3; ++tap) {
            half8 aw0 = *(const half8*)(wstage + (tap * 4 + 0) * 256 + (lane << 2));
            half8 aw1 = *(const half8*)(wstage + (tap * 4 + 1) * 256 + (lane << 2));
            half8 aw2 = *(const half8*)(wstage + (tap * 4 + 2) * 256 + (lane << 2));
            half8 aw3 = *(const half8*)(wstage + (tap * 4 + 3) * 256 + (lane << 2));
            int r0 = row0a + (tap - 1) * d + col0;
            r0 = r0 < 0 ? 0 : (r0 > NROWS - 1 ? NROWS - 1 : r0);
            int r1 = row0b + (tap - 1) * d + col0;
            r1 = r1 < 0 ? 0 : (r1 > NROWS - 1 ? NROWS - 1 : r1);
            const unsigned* hp0 = cur + r0 * HS + g4 * 4;
            const unsigned* hp1 = cur + r1 * HS + g4 * 4;
            AFR bf0; bf0.u2[0] = *(const uint2*)hp0; bf0.u2[1] = *(const uint2*)(hp0 + 2);
            AFR bf1; bf1.u2[0] = *(const uint2*)hp1; bf1.u2[1] = *(const uint2*)(hp1 + 2);
            if (tap == 1) {   // (tap-1)*d == 0 -> same address as the old hold read
                hb0a = bf0.u2[0]; hb0b = bf0.u2[1];
                hb1a = bf1.u2[0]; hb1b = bf1.u2[1];
            }
            a0 = MFMA(aw0, bf0.v, a0);  a4 = MFMA(aw0, bf1.v, a4);
            a1 = MFMA(aw1, bf0.v, a1);  a5 = MFMA(aw1, bf1.v, a5);
            a2 = MFMA(aw2, bf0.v, a2);  a6 = MFMA(aw2, bf1.v, a6);
            a3 = MFMA(aw3, bf0.v, a3);  a7 = MFMA(aw3, bf1.v, a7);
        }

        // skip weights (last wstage reads of iter i)
        half8 skw0 = *(const half8*)(wstage + STG_SKIP + (lane << 2));
        half8 skw1 = *(const half8*)(wstage + STG_SKIP + 256 + (lane << 2));

        // EARLY staging barrier: all waves' wstage reads of iter i done ->
        // overwrite with iter i+1 weights NOW; the DMA flies under the gates
        // (48 quarter-rate transcendentals) + BACKs (~700 cy) and is fully
        // landed by the iter-end barrier's vmcnt drain.
        if (!ilast) {
            __syncthreads();
            STAGE_ITER(i + 1);
        }

        // ---- gates: consume 32 accs into 2 packed z fragments ----
        AFR zf0, zf1;
        {
            float za0 = gated(a0[0], a2[0]), za1 = gated(a0[1], a2[1]);
            float za2 = gated(a0[2], a2[2]), za3 = gated(a0[3], a2[3]);
            float zb0 = gated(a1[0], a3[0]), zb1 = gated(a1[1], a3[1]);
            float zb2 = gated(a1[2], a3[2]), zb3 = gated(a1[3], a3[3]);
            zf0.u2[0] = make_uint2(packh(za0, za1), packh(za2, za3));
            zf0.u2[1] = make_uint2(packh(zb0, zb1), packh(zb2, zb3));
        }
        {
            float za0 = gated(a4[0], a6[0]), za1 = gated(a4[1], a6[1]);
            float za2 = gated(a4[2], a6[2]), za3 = gated(a4[3], a6[3]);
            float zb0 = gated(a5[0], a7[0]), zb1 = gated(a5[1], a7[1]);
            float zb2 = gated(a5[2], a7[2]), zb3 = gated(a5[3], a7[3]);
            zf1.u2[0] = make_uint2(packh(za0, za1), packh(za2, za3));
            zf1.u2[1] = make_uint2(packh(zb0, zb1), packh(zb2, zb3));
        }

        // skip bias C-init read once, shared by both BACKs
        f32x4 bk_lo = *(const f32x4*)&bias_s[2 * NBLK * 32 + i * 32 + 4 * g4];
        f32x4 bk_hi = *(const f32x4*)&bias_s[2 * NBLK * 32 + i * 32 + 16 + 4 * g4];

        BACK_SEG(row0a, zf0, hb0a, hb0b);
        BACK_SEG(row0b, zf1, hb1a, hb1b);

        // iter-end barrier: nxt complete across waves + weight DMA drained.
        // Dead at i=5: the final section reads only same-lane rows of ybuf.
        if (!ilast) __syncthreads();
    }
    asm volatile("" ::: "memory");   // order i=5 h-writes before ybuf reads

    // ---- final 1x1 conv (swapped) + dense partial ----
    // w_dense prefetch FIRST (clamped addresses) so cold-HBM latency overlaps
    // the final MFMAs. Layout: float idx = tgr*64 + ch*2 + cls.
    float4 wdp[2][4];
    #pragma unroll
    for (int mt = 0; mt < 2; ++mt) {
        int row = wv * 32 + mt * 16 + col0;
        int tgr = tile * TILE - HALO + row;
        tgr = tgr < 0 ? 0 : (tgr > T_LEN - 1 ? T_LEN - 1 : tgr);
        const float* base = w_dense + (size_t)tgr * 64;
        wdp[mt][0] = *(const float4*)(base + 8 * g4);
        wdp[mt][1] = *(const float4*)(base + 8 * g4 + 4);
        wdp[mt][2] = *(const float4*)(base + 32 + 8 * g4);
        wdp[mt][3] = *(const float4*)(base + 32 + 8 * g4 + 4);
    }

    const unsigned* ybuf = &h_pack[(NBLK & 1) * HBUF];
    half8 fwA[2];
    fwA[0] = *(const half8*)(wsB + WS_FIN + (lane << 2));
    fwA[1] = *(const half8*)(wsB + WS_FIN + 256 + (lane << 2));
    float4 bfa = *(const float4*)&b_final[4 * g4];
    float4 bfb = *(const float4*)&b_final[16 + 4 * g4];
    float pa = 0.0f, pb = 0.0f;

    #pragma unroll
    for (int mt = 0; mt < 2; ++mt) {
        const int row = wv * 32 + mt * 16 + col0;
        const unsigned* ya = ybuf + row * HS + g4 * 4;
        AFR ay; ay.u2[0] = *(const uint2*)ya; ay.u2[1] = *(const uint2*)(ya + 2);
        f32x4 f0 = (f32x4){bfa.x, bfa.y, bfa.z, bfa.w};
        f32x4 f1 = (f32x4){bfb.x, bfb.y, bfb.z, bfb.w};
        f0 = MFMA(fwA[0], ay.v, f0);
        f1 = MFMA(fwA[1], ay.v, f1);
        if (row >= HALO && row < HALO + TILE) {
            float v;
            v = relu(f0[0]); pa = fmaf(v, wdp[mt][0].x, pa); pb = fmaf(v, wdp[mt][0].y, pb);
            v = relu(f0[1]); pa = fmaf(v, wdp[mt][0].z, pa); pb = fmaf(v, wdp[mt][0].w, pb);
            v = relu(f0[2]); pa = fmaf(v, wdp[mt][1].x, pa); pb = fmaf(v, wdp[mt][1].y, pb);
            v = relu(f0[3]); pa = fmaf(v, wdp[mt][1].z, pa); pb = fmaf(v, wdp[mt][1].w, pb);
            v = relu(f1[0]); pa = fmaf(v, wdp[mt][2].x, pa); pb = fmaf(v, wdp[mt][2].y, pb);
            v = relu(f1[1]); pa = fmaf(v, wdp[mt][2].z, pa); pb = fmaf(v, wdp[mt][2].w, pb);
            v = relu(f1[2]); pa = fmaf(v, wdp[mt][3].x, pa); pb = fmaf(v, wdp[mt][3].y, pb);
            v = relu(f1[3]); pa = fmaf(v, wdp[mt][3].z, pa); pb = fmaf(v, wdp[mt][3].w, pb);
        }
    }

    // block reduction -> logits; last-arriving block does the softmax.
    // Tail parallelized across wave-0 lanes (3 atomic RTs vs 19 serialized).
    #pragma unroll
    for (int off = 32; off > 0; off >>= 1) {
        pa += __shfl_down(pa, off);
        pb += __shfl_down(pb, off);
    }
    if (lane == 0) { red[wv][0] = pa; red[wv][1] = pb; }
    __syncthreads();
    if (wv == 0) {
        if (lane < 2) {
            float s = 0.0f;
            #pragma unroll
            for (int w = 0; w < NWAVE; ++w) s += red[w][lane];
            atomicAdd(&logits[b * 2 + lane], s);
        }
        __threadfence();                       // release: logits adds before counter
        unsigned arrived = 0u;
        if (lane == 0) arrived = atomicAdd(counter, 1u);
        arrived = __builtin_amdgcn_readfirstlane(arrived);
        if (arrived == (unsigned)(NBATCH * NTILES - 1)) {
            __threadfence();                   // acquire
            float l = 0.0f;
            if (lane < 16)
                l = atomicAdd(&logits[lane], 0.0f) + b_dense[lane & 1];
            float lx = __shfl_xor(l, 1);
            float m  = fmaxf(l, lx);
            float e  = __expf(l - m);
            float ex = __shfl_xor(e, 1);
            float r  = e * __builtin_amdgcn_rcpf(e + ex);
            if (lane < 16) out[lane] = r;
        }
    }
    #undef STAGE_ITER
    #undef BACK_SEG
}

extern "C" void kernel_launch(void* const* d_in, const int* in_sizes, int n_in,
                              void* d_out, int out_size, void* d_ws, size_t ws_size,
                              hipStream_t stream) {
    const float* x       = (const float*)d_in[0];
    const float* w_init  = (const float*)d_in[1];
    const float* b_init  = (const float*)d_in[2];
    const float* w_tanh  = (const float*)d_in[3];
    const float* b_tanh  = (const float*)d_in[4];
    const float* w_sig   = (const float*)d_in[5];
    const float* b_sig   = (const float*)d_in[6];
    const float* w_skip  = (const float*)d_in[7];
    const float* b_skip  = (const float*)d_in[8];
    const float* w_final = (const float*)d_in[9];
    const float* b_final = (const float*)d_in[10];
    const float* w_dense = (const float*)d_in[11];
    const float* b_dense = (const float*)d_in[12];

    unsigned* wsB     = (unsigned*)d_ws;
    float*    logits  = (float*)d_ws + WS_LOG;
    unsigned* counter = (unsigned*)d_ws + WS_CNT;

    wavenet_prep<<<(PREP_TOT + 255) / 256, 256, 0, stream>>>(w_tanh, w_sig, w_skip, w_final, wsB);
    wavenet_main<<<NBATCH * NTILES, NTHR, 0, stream>>>(
        x, w_init, b_init, b_tanh, b_sig, b_skip, b_final, b_dense, w_dense,
        wsB, logits, counter, (float*)d_out);
}

// Round 19
// 114.976 us; speedup vs baseline: 1.0395x; 1.0395x over previous
//
#include <hip/hip_runtime.h>
#include <math.h>

#define T_LEN   16384
#define NBATCH  8
#define NBLK    6
#define TILE    256
#define HALO    63
#define NTHR    768          // 12 waves; each wave owns 32 rows (2 m-tiles)
#define NWAVE   12
#define NROWS   384          // TILE + 2*HALO = 382, padded to 384
#define NTILES  64
#define HS      18           // f16 row stride in dwords (72 B)
#define HBUF    (NROWS * HS) // one h buffer in dwords

// workspace layout (dwords)
#define WS_CONV 0             // [i6][tap3][nt4][lane64][dw4] = 18432
#define WS_SKIP 18432         // [i6][nt2][lane64][dw4]      = 3072
#define WS_FIN  21504         // [nt2][lane64][dw4]          = 512
#define WS_LOG  22016         // 16 floats logits
#define WS_CNT  22032         // 1 uint completion counter
#define PREP_N  22016
#define PREP_TOT 22036

// per-iter LDS weight stage: 12 conv chunks + 2 skip chunks, 256 dw each
#define STG_CONV 0            // [tap3][nt4][lane64][dw4] = 3072 dw
#define STG_SKIP 3072         // [nt2][lane64][dw4]       = 512 dw
#define STG_TOT  3584         // 14336 B

// exp2-domain pre-scaling: tanh path x 2*log2(e), sigmoid path x log2(e).
#define SCALE_T 2.8853900817779268f
#define SCALE_S 1.4426950408889634f

typedef _Float16 half8 __attribute__((ext_vector_type(8)));
typedef __fp16  fp16x2 __attribute__((ext_vector_type(2)));   // cvt_pkrtz result type
typedef _Float16 h2v   __attribute__((ext_vector_type(2)));   // arithmetic type
typedef float f32x4  __attribute__((ext_vector_type(4)));

union HPK { unsigned u; _Float16 h[2]; fp16x2 pk; h2v v; };   // same 32 bits, two views
union AFR { uint2 u2[2]; half8 v; };

__device__ __forceinline__ unsigned packh(float a, float b) {   // 1x v_cvt_pkrtz_f16_f32
    HPK r; r.pk = __builtin_amdgcn_cvt_pkrtz(a, b); return r.u;
}
__device__ __forceinline__ h2v u2h(unsigned u) { HPK c; c.u = u; return c.v; }
__device__ __forceinline__ unsigned h2u(h2v h) { HPK c; c.v = h; return c.u; }
// packed relu: v_pk_max_f16 with 0
__device__ __forceinline__ h2v pkmax0(h2v a) {
    const h2v z = {(_Float16)0.0f, (_Float16)0.0f};
    return __builtin_elementwise_max(a, z);
}

// K-slot <-> logical-channel permutation shared by ALL operand-swapped MFMAs.
__device__ __forceinline__ int perm_ch(int g, int j) {
    return j < 4 ? 4 * g + j : 16 + 4 * g + (j - 4);
}

// tanh*sigmoid on PRE-SCALED args (exp2 domain). 3 quarter-rate ops.
__device__ __forceinline__ float gated(float a, float b) {
    float ea  = __builtin_amdgcn_exp2f(-fabsf(a));   // v_exp_f32 w/ -abs modifier
    float fb  = __builtin_amdgcn_exp2f(-b);          // v_exp_f32 w/ neg modifier
    float num = 1.0f - ea;
    float den = (1.0f + ea) * (1.0f + fb);
    float t   = num * __builtin_amdgcn_rcpf(den);
    return __builtin_copysignf(t, a);
}
__device__ __forceinline__ float relu(float x) { return fmaxf(x, 0.0f); }

// async global->LDS DMA, 16B per lane, wave-linear dest (base + lane*16)
__device__ __forceinline__ void gl_lds16(const unsigned* g, unsigned* l) {
    __builtin_amdgcn_global_load_lds(
        (const __attribute__((address_space(1))) void*)g,
        (__attribute__((address_space(3))) void*)l, 16, 0, 0);
}

#define MFMA(a, b, c) __builtin_amdgcn_mfma_f32_16x16x32_f16((a), (b), (c), 0, 0, 0)

// ---------------- weight prep: fp32 -> f16 A-fragments (operand-swapped) ----------------
__global__ void wavenet_prep(const float* __restrict__ wt, const float* __restrict__ wsg,
                             const float* __restrict__ wsk, const float* __restrict__ wfin,
                             unsigned* __restrict__ out)
{
    int id = blockIdx.x * 256 + threadIdx.x;
    if (id >= PREP_TOT) return;
    if (id >= PREP_N) { out[id] = 0u; return; }   // zero logits + counter
    int dw = id & 3, lane = (id >> 2) & 63;
    int g = lane >> 4, nlo = lane & 15;
    int ci0 = perm_ch(g, 2 * dw), ci1 = perm_ch(g, 2 * dw + 1);
    float v0, v1;
    if (id < WS_SKIP) {
        int nt = (id >> 8) & 3; int q = id >> 10;  // q = i*3+tap
        int tap = q % 3, i = q / 3;
        int co = (nt & 1) * 16 + nlo;
        const float* src = (nt < 2) ? wt : wsg;
        float sc = (nt < 2) ? SCALE_T : SCALE_S;
        v0 = src[((i * 3 + tap) * 32 + ci0) * 32 + co] * sc;
        v1 = src[((i * 3 + tap) * 32 + ci1) * 32 + co] * sc;
    } else if (id < WS_FIN) {
        int t = id - WS_SKIP;
        int nt = (t >> 8) & 1; int i = t >> 9;
        int co = nt * 16 + nlo;
        v0 = wsk[(i * 32 + ci0) * 32 + co];
        v1 = wsk[(i * 32 + ci1) * 32 + co];
    } else {
        int t = id - WS_FIN;
        int nt = (t >> 8) & 1;
        int co = nt * 16 + nlo;
        v0 = wfin[ci0 * 32 + co];
        v1 = wfin[ci1 * 32 + co];
    }
    HPK r; r.h[0] = (_Float16)v0; r.h[1] = (_Float16)v1;   // RNE for weights
    out[id] = r.u;
}

// ---------------- main fused kernel ----------------
// SESSION-BEST STATE (r29, verified twice: 41.3/41.0us main, 115.8us harness).
// Ladder: r23 operand-swapped MFMAs (z in regs, conflicts 1.87M->98K);
// r24 liveness schedule; r27 packed-f16 epilogue; r28 exp2-domain gates;
// r29 segment-fused conv (shared weight reads, shared bias C-inits, hold =
// tap-1 fragment register-reuse). Residual ~3-dword spill (WRITE 4.6MB),
// conv peak ~86 regs vs the (768,6) 85-reg cap.
// FALSIFIED alternatives -- do not retry:
//  r30 source-order resequencing + hold-from-LDS: spill 4.6->16.9MB, 49.5us
//    (source block order does NOT control scheduler liveness).
//  r31 early staging barrier: accs live across barrier -> 13.9MB, 44us.
//  r32 TILE=512 / 1280-thread block: INVALID LAUNCH -- MI355X max workgroup
//    = 1024 threads (16 waves). TILE=512 has no clean 16-row-segment split
//    within that cap (40 segments / 16 waves -> 3-segment critical path).
// Kernel is lockstep-latency-bound at the register cap; every probed
// perturbation spills or violates a HW limit. This is the stable optimum
// for this structure.
// Ordering by barriers only (r21: NEVER volatile on LDS pointers).
__global__ __launch_bounds__(NTHR, 6)
void wavenet_main(const float* __restrict__ x,
                  const float* __restrict__ w_init, const float* __restrict__ b_init,
                  const float* __restrict__ b_tanh, const float* __restrict__ b_sig,
                  const float* __restrict__ b_skip, const float* __restrict__ b_final,
                  const float* __restrict__ b_dense,
                  const float* __restrict__ w_dense,
                  const unsigned* __restrict__ wsB,
                  float* __restrict__ logits, unsigned* __restrict__ counter,
                  float* __restrict__ out)
{
    __shared__ unsigned h_pack[2 * HBUF];      // double-buffered, 55296 B
    __shared__ unsigned wstage[STG_TOT];       // per-iter weight stage, 14336 B
    __shared__ unsigned x_s[NROWS];            // packed f16 (xv,xv), 1536 B
    __shared__ float bias_s[3 * NBLK * 32];    // [t/s/k][i][ch], 2304 B (t/s pre-scaled)
    __shared__ unsigned wibp_s[32];            // packed f16 w_init[16] + b_init[16], slot order
    __shared__ float red[NWAVE][2];

    const int tid  = threadIdx.x;
    const int lane = tid & 63;
    const int wv   = tid >> 6;               // 0..11; wave owns rows [wv*32, wv*32+32)
    const int tile = blockIdx.x & (NTILES - 1);
    const int b    = blockIdx.x >> 6;
    const int col0 = lane & 15;              // = time-row within 16-row segment
    const int g4   = lane >> 4;              // k-slot group / slot quad

    // stage iter-`it` weights: wave wv takes conv chunk wv, waves 0/1 also skip chunks
    #define STAGE_ITER(it) do {                                                   \
        const unsigned* _s = wsB + (it) * 3072 + wv * 256 + (lane << 2);          \
        gl_lds16(_s, wstage + wv * 256 + (lane << 2));                            \
        if (wv < 2) {                                                             \
            const unsigned* _s2 = wsB + WS_SKIP + (it) * 512 + wv * 256 + (lane << 2); \
            gl_lds16(_s2, wstage + STG_SKIP + wv * 256 + (lane << 2));            \
        }                                                                         \
    } while (0)

    // skip MFMA + packed-f16 h update for one segment. ZF/HB/skw/bk all in regs.
    #define BACK_SEG(ROW0, ZF, HBA, HBB) do {                                     \
        f32x4 s0 = bk_lo, s1 = bk_hi;                                             \
        s0 = MFMA(skw0, (ZF).v, s0);                                              \
        s1 = MFMA(skw1, (ZF).v, s1);                                              \
        const int row = (ROW0) + col0;                                            \
        h2v n0 = pkmax0(u2h(packh(s0[0], s0[1]))) + u2h((HBA).x);                 \
        h2v n1 = pkmax0(u2h(packh(s0[2], s0[3]))) + u2h((HBA).y);                 \
        h2v n2 = pkmax0(u2h(packh(s1[0], s1[1]))) + u2h((HBB).x);                 \
        h2v n3 = pkmax0(u2h(packh(s1[2], s1[3]))) + u2h((HBB).y);                 \
        unsigned pk0, pk1, pk2, pk3;                                              \
        if (!ilast) {                                                             \
            int tgr = tile * TILE - HALO + row;                                   \
            bool vr = (tgr >= 0) && (tgr < T_LEN);                                \
            pk0 = vr ? h2u(n0) : 0u;                                              \
            pk1 = vr ? h2u(n1) : 0u;                                              \
            pk2 = vr ? h2u(n2) : 0u;                                              \
            pk3 = vr ? h2u(n3) : 0u;                                              \
        } else {                                                                  \
            h2v xh = u2h(x_s[row]);                                               \
            uint2 wpA = *(const uint2*)&wibp_s[4 * g4];                           \
            uint2 wpB = *(const uint2*)&wibp_s[4 * g4 + 2];                       \
            uint2 bpA = *(const uint2*)&wibp_s[16 + 4 * g4];                      \
            uint2 bpB = *(const uint2*)&wibp_s[16 + 4 * g4 + 2];                  \
            h2v h00 = pkmax0(xh * u2h(wpA.x) + u2h(bpA.x));                       \
            h2v h01 = pkmax0(xh * u2h(wpA.y) + u2h(bpA.y));                       \
            h2v h02 = pkmax0(xh * u2h(wpB.x) + u2h(bpB.x));                       \
            h2v h03 = pkmax0(xh * u2h(wpB.y) + u2h(bpB.y));                       \
            pk0 = h2u(pkmax0(n0 - h00));                                          \
            pk1 = h2u(pkmax0(n1 - h01));                                          \
            pk2 = h2u(pkmax0(n2 - h02));                                          \
            pk3 = h2u(pkmax0(n3 - h03));                                          \
        }                                                                         \
        unsigned* hw = nxt + row * HS + g4 * 4;                                   \
        *(uint2*)hw = make_uint2(pk0, pk1);                                       \
        *(uint2*)(hw + 2) = make_uint2(pk2, pk3);                                 \
    } while (0)

    // ---- issue DMA for iter-0 weights immediately (lands before first barrier drain) ----
    STAGE_ITER(0);

    // ---- stage biases (gate paths pre-scaled) + packed init weights into LDS ----
    if (tid < 3 * NBLK * 32) {
        int which = tid / (NBLK * 32), r = tid % (NBLK * 32);
        float v = (which == 0) ? b_tanh[r] * SCALE_T
                : (which == 1) ? b_sig[r] * SCALE_S : b_skip[r];
        bias_s[tid] = v;
    } else if (tid < 3 * NBLK * 32 + 16) {
        int q  = tid - 3 * NBLK * 32;            // dword 0..15 (slot order)
        int c0 = perm_ch((2 * q) >> 3, (2 * q) & 7);
        int c1 = perm_ch((2 * q + 1) >> 3, (2 * q + 1) & 7);
        HPK w; w.h[0] = (_Float16)w_init[c0]; w.h[1] = (_Float16)w_init[c1];
        HPK bb2; bb2.h[0] = (_Float16)b_init[c0]; bb2.h[1] = (_Float16)b_init[c1];
        wibp_s[q]      = w.u;
        wibp_s[16 + q] = bb2.u;
    }

    // ---- init conv (CIN=1) -> f16 h in buf0 (SLOT channel order); 2 threads/row ----
    {
        int j    = tid >> 1;                 // row 0..383
        int half = tid & 1;                  // dwords half*8 .. half*8+7
        int tg = tile * TILE - HALO + j;
        bool valid = (tg >= 0) && (tg < T_LEN);
        float xv = valid ? x[(size_t)b * T_LEN + tg] : 0.0f;
        x_s[j] = packh(xv, xv);              // both halves write same value (benign)
        unsigned* hp = &h_pack[j * HS + half * 8];
        #pragma unroll
        for (int q = 0; q < 4; ++q) {
            unsigned pk[2];
            #pragma unroll
            for (int e = 0; e < 2; ++e) {
                int D  = half * 8 + 2 * q + e;           // dword index in row
                int s0 = 2 * D, s1 = 2 * D + 1;          // slot indices
                int c0 = perm_ch(s0 >> 3, s0 & 7);
                int c1 = perm_ch(s1 >> 3, s1 & 7);
                float f0 = relu(fmaf(xv, w_init[c0], b_init[c0]));
                float f1 = relu(fmaf(xv, w_init[c1], b_init[c1]));
                pk[e] = valid ? packh(f0, f1) : 0u;
            }
            *(uint2*)(hp + 2 * q) = make_uint2(pk[0], pk[1]);
        }
    }
    __syncthreads();    // drains vmcnt too -> iter-0 weight DMA landed

    #pragma unroll
    for (int i = 0; i < NBLK; ++i) {
        const int d = 1 << i;
        const unsigned* cur = &h_pack[(i & 1) * HBUF];
        unsigned*       nxt = &h_pack[((i + 1) & 1) * HBUF];
        const bool ilast = (i == NBLK - 1);
        const int row0a = wv * 32;
        const int row0b = wv * 32 + 16;

        // ---- fused conv: both segments share each tap's weight read ----
        // bias C-inits read ONCE, copied into both segments' accumulators.
        f32x4 bt_lo = *(const f32x4*)&bias_s[0 * NBLK * 32 + i * 32 + 4 * g4];
        f32x4 bt_hi = *(const f32x4*)&bias_s[0 * NBLK * 32 + i * 32 + 16 + 4 * g4];
        f32x4 bs_lo = *(const f32x4*)&bias_s[1 * NBLK * 32 + i * 32 + 4 * g4];
        f32x4 bs_hi = *(const f32x4*)&bias_s[1 * NBLK * 32 + i * 32 + 16 + 4 * g4];
        f32x4 a0 = bt_lo, a1 = bt_hi, a2 = bs_lo, a3 = bs_hi;   // seg0
        f32x4 a4 = bt_lo, a5 = bt_hi, a6 = bs_lo, a7 = bs_hi;   // seg1
        uint2 hb0a, hb0b, hb1a, hb1b;                           // tap-1 frags = hold

        #pragma unroll
        for (int tap = 0; tap < 3; ++tap) {
            half8 aw0 = *(const half8*)(wstage + (tap * 4 + 0) * 256 + (lane << 2));
            half8 aw1 = *(const half8*)(wstage + (tap * 4 + 1) * 256 + (lane << 2));
            half8 aw2 = *(const half8*)(wstage + (tap * 4 + 2) * 256 + (lane << 2));
            half8 aw3 = *(const half8*)(wstage + (tap * 4 + 3) * 256 + (lane << 2));
            int r0 = row0a + (tap - 1) * d + col0;
            r0 = r0 < 0 ? 0 : (r0 > NROWS - 1 ? NROWS - 1 : r0);
            int r1 = row0b + (tap - 1) * d + col0;
            r1 = r1 < 0 ? 0 : (r1 > NROWS - 1 ? NROWS - 1 : r1);
            const unsigned* hp0 = cur + r0 * HS + g4 * 4;
            const unsigned* hp1 = cur + r1 * HS + g4 * 4;
            AFR bf0; bf0.u2[0] = *(const uint2*)hp0; bf0.u2[1] = *(const uint2*)(hp0 + 2);
            AFR bf1; bf1.u2[0] = *(const uint2*)hp1; bf1.u2[1] = *(const uint2*)(hp1 + 2);
            if (tap == 1) {   // (tap-1)*d == 0 -> same address as the old hold read
                hb0a = bf0.u2[0]; hb0b = bf0.u2[1];
                hb1a = bf1.u2[0]; hb1b = bf1.u2[1];
            }
            a0 = MFMA(aw0, bf0.v, a0);  a4 = MFMA(aw0, bf1.v, a4);
            a1 = MFMA(aw1, bf0.v, a1);  a5 = MFMA(aw1, bf1.v, a5);
            a2 = MFMA(aw2, bf0.v, a2);  a6 = MFMA(aw2, bf1.v, a6);
            a3 = MFMA(aw3, bf0.v, a3);  a7 = MFMA(aw3, bf1.v, a7);
        }

        // ---- gates: consume 32 accs into 2 packed z fragments ----
        AFR zf0, zf1;
        {
            float za0 = gated(a0[0], a2[0]), za1 = gated(a0[1], a2[1]);
            float za2 = gated(a0[2], a2[2]), za3 = gated(a0[3], a2[3]);
            float zb0 = gated(a1[0], a3[0]), zb1 = gated(a1[1], a3[1]);
            float zb2 = gated(a1[2], a3[2]), zb3 = gated(a1[3], a3[3]);
            zf0.u2[0] = make_uint2(packh(za0, za1), packh(za2, za3));
            zf0.u2[1] = make_uint2(packh(zb0, zb1), packh(zb2, zb3));
        }
        {
            float za0 = gated(a4[0], a6[0]), za1 = gated(a4[1], a6[1]);
            float za2 = gated(a4[2], a6[2]), za3 = gated(a4[3], a6[3]);
            float zb0 = gated(a5[0], a7[0]), zb1 = gated(a5[1], a7[1]);
            float zb2 = gated(a5[2], a7[2]), zb3 = gated(a5[3], a7[3]);
            zf1.u2[0] = make_uint2(packh(za0, za1), packh(za2, za3));
            zf1.u2[1] = make_uint2(packh(zb0, zb1), packh(zb2, zb3));
        }

        // skip weights (wstage -- must be read before the staging barrier)
        half8 skw0 = *(const half8*)(wstage + STG_SKIP + (lane << 2));
        half8 skw1 = *(const half8*)(wstage + STG_SKIP + 256 + (lane << 2));

        // staging barrier: all waves' wstage reads of iter i done -> overwrite
        // with iter i+1 weights; DMA flies under the BACKs + barrier drain.
        if (!ilast) {
            __syncthreads();
            STAGE_ITER(i + 1);
        }

        // skip bias C-init read once, shared by both BACKs
        f32x4 bk_lo = *(const f32x4*)&bias_s[2 * NBLK * 32 + i * 32 + 4 * g4];
        f32x4 bk_hi = *(const f32x4*)&bias_s[2 * NBLK * 32 + i * 32 + 16 + 4 * g4];

        BACK_SEG(row0a, zf0, hb0a, hb0b);
        BACK_SEG(row0b, zf1, hb1a, hb1b);

        // iter-end barrier: nxt complete across waves + weight DMA drained.
        // Dead at i=5: the final section reads only same-lane rows of ybuf.
        if (!ilast) __syncthreads();
    }
    asm volatile("" ::: "memory");   // order i=5 h-writes before ybuf reads

    // ---- final 1x1 conv (swapped) + dense partial ----
    // w_dense prefetch FIRST (clamped addresses) so cold-HBM latency overlaps
    // the final MFMAs. Layout: float idx = tgr*64 + ch*2 + cls.
    float4 wdp[2][4];
    #pragma unroll
    for (int mt = 0; mt < 2; ++mt) {
        int row = wv * 32 + mt * 16 + col0;
        int tgr = tile * TILE - HALO + row;
        tgr = tgr < 0 ? 0 : (tgr > T_LEN - 1 ? T_LEN - 1 : tgr);
        const float* base = w_dense + (size_t)tgr * 64;
        wdp[mt][0] = *(const float4*)(base + 8 * g4);
        wdp[mt][1] = *(const float4*)(base + 8 * g4 + 4);
        wdp[mt][2] = *(const float4*)(base + 32 + 8 * g4);
        wdp[mt][3] = *(const float4*)(base + 32 + 8 * g4 + 4);
    }

    const unsigned* ybuf = &h_pack[(NBLK & 1) * HBUF];
    half8 fwA[2];
    fwA[0] = *(const half8*)(wsB + WS_FIN + (lane << 2));
    fwA[1] = *(const half8*)(wsB + WS_FIN + 256 + (lane << 2));
    float4 bfa = *(const float4*)&b_final[4 * g4];
    float4 bfb = *(const float4*)&b_final[16 + 4 * g4];
    float pa = 0.0f, pb = 0.0f;

    #pragma unroll
    for (int mt = 0; mt < 2; ++mt) {
        const int row = wv * 32 + mt * 16 + col0;
        const unsigned* ya = ybuf + row * HS + g4 * 4;
        AFR ay; ay.u2[0] = *(const uint2*)ya; ay.u2[1] = *(const uint2*)(ya + 2);
        f32x4 f0 = (f32x4){bfa.x, bfa.y, bfa.z, bfa.w};
        f32x4 f1 = (f32x4){bfb.x, bfb.y, bfb.z, bfb.w};
        f0 = MFMA(fwA[0], ay.v, f0);
        f1 = MFMA(fwA[1], ay.v, f1);
        if (row >= HALO && row < HALO + TILE) {
            float v;
            v = relu(f0[0]); pa = fmaf(v, wdp[mt][0].x, pa); pb = fmaf(v, wdp[mt][0].y, pb);
            v = relu(f0[1]); pa = fmaf(v, wdp[mt][0].z, pa); pb = fmaf(v, wdp[mt][0].w, pb);
            v = relu(f0[2]); pa = fmaf(v, wdp[mt][1].x, pa); pb = fmaf(v, wdp[mt][1].y, pb);
            v = relu(f0[3]); pa = fmaf(v, wdp[mt][1].z, pa); pb = fmaf(v, wdp[mt][1].w, pb);
            v = relu(f1[0]); pa = fmaf(v, wdp[mt][2].x, pa); pb = fmaf(v, wdp[mt][2].y, pb);
            v = relu(f1[1]); pa = fmaf(v, wdp[mt][2].z, pa); pb = fmaf(v, wdp[mt][2].w, pb);
            v = relu(f1[2]); pa = fmaf(v, wdp[mt][3].x, pa); pb = fmaf(v, wdp[mt][3].y, pb);
            v = relu(f1[3]); pa = fmaf(v, wdp[mt][3].z, pa); pb = fmaf(v, wdp[mt][3].w, pb);
        }
    }

    // block reduction -> logits; last-arriving block does the softmax.
    // Tail parallelized across wave-0 lanes (3 atomic RTs vs 19 serialized).
    #pragma unroll
    for (int off = 32; off > 0; off >>= 1) {
        pa += __shfl_down(pa, off);
        pb += __shfl_down(pb, off);
    }
    if (lane == 0) { red[wv][0] = pa; red[wv][1] = pb; }
    __syncthreads();
    if (wv == 0) {
        if (lane < 2) {
            float s = 0.0f;
            #pragma unroll
            for (int w = 0; w < NWAVE; ++w) s += red[w][lane];
            atomicAdd(&logits[b * 2 + lane], s);
        }
        __threadfence();                       // release: logits adds before counter
        unsigned arrived = 0u;
        if (lane == 0) arrived = atomicAdd(counter, 1u);
        arrived = __builtin_amdgcn_readfirstlane(arrived);
        if (arrived == (unsigned)(NBATCH * NTILES - 1)) {
            __threadfence();                   // acquire
            float l = 0.0f;
            if (lane < 16)
                l = atomicAdd(&logits[lane], 0.0f) + b_dense[lane & 1];
            float lx = __shfl_xor(l, 1);
            float m  = fmaxf(l, lx);
            float e  = __expf(l - m);
            float ex = __shfl_xor(e, 1);
            float r  = e * __builtin_amdgcn_rcpf(e + ex);
            if (lane < 16) out[lane] = r;
        }
    }
    #undef STAGE_ITER
    #undef BACK_SEG
}

extern "C" void kernel_launch(void* const* d_in, const int* in_sizes, int n_in,
                              void* d_out, int out_size, void* d_ws, size_t ws_size,
                              hipStream_t stream) {
    const float* x       = (const float*)d_in[0];
    const float* w_init  = (const float*)d_in[1];
    const float* b_init  = (const float*)d_in[2];
    const float* w_tanh  = (const float*)d_in[3];
    const float* b_tanh  = (const float*)d_in[4];
    const float* w_sig   = (const float*)d_in[5];
    const float* b_sig   = (const float*)d_in[6];
    const float* w_skip  = (const float*)d_in[7];
    const float* b_skip  = (const float*)d_in[8];
    const float* w_final = (const float*)d_in[9];
    const float* b_final = (const float*)d_in[10];
    const float* w_dense = (const float*)d_in[11];
    const float* b_dense = (const float*)d_in[12];

    unsigned* wsB     = (unsigned*)d_ws;
    float*    logits  = (float*)d_ws + WS_LOG;
    unsigned* counter = (unsigned*)d_ws + WS_CNT;

    wavenet_prep<<<(PREP_TOT + 255) / 256, 256, 0, stream>>>(w_tanh, w_sig, w_skip, w_final, wsB);
    wavenet_main<<<NBATCH * NTILES, NTHR, 0, stream>>>(
        x, w_init, b_init, b_tanh, b_sig, b_skip, b_final, b_dense, w_dense,
        wsB, logits, counter, (float*)d_out);
}